// Round 12
// baseline (1741.970 us; speedup 1.0000x reference)
//
#include <hip/hip_runtime.h>
#include <hip/hip_bf16.h>

// Grouped experts FFN. E=8, C=2048, D=2048, F=8192.
// y[e] = GELU(x[e] @ W1[e] + b1[e]) @ W2[e] + b2[e]
// R12: R7 skeleton with B TAKEN OUT OF LDS.
//   A: unchanged (global_load_lds DMA, 2 slots x 2 regions x 16KB = 64KB,
//      XOR-swizzled source, counted-vmcnt checkpoints).
//   B: each wave loads its own fragments global->VGPR, register ping-pong
//      one phase ahead (P0 consumes bA / loads bB; P1 consumes bB / loads
//      bA for T+1). B panel is 2-way shared in-block with identical
//      addresses -> L1 dedupes; LDS traffic drops 288->160 KB/K-tile.
//   vm queue: 6 ops/phase (4 B-loads + 2 A-DMA); checkpoint vmcnt(12)
//   guarantees A staged 2 phases ago; prologue [A0(0),A1(0),B(P0(0)),A0(1)]
//   + vmcnt(8) primes exact counts. Compiler adds its own b-reg waits.

#define E_ 8
#define C_ 2048
#define D_ 2048
#define F_ 8192

typedef short bf16x8 __attribute__((ext_vector_type(8)));
typedef float f32x4  __attribute__((ext_vector_type(4)));

__device__ inline unsigned short f2bf(float f) {
    unsigned u = __float_as_uint(f);
    u += 0x7fffu + ((u >> 16) & 1u);
    return (unsigned short)(u >> 16);
}

__device__ inline float gelu_fast(float x) {
    float z = 0.7978845608028654f * (x + 0.044715f * x * x * x);
    float e = __expf(-2.0f * fabsf(z));
    float t = (1.0f - e) / (1.0f + e);
    t = copysignf(t, z);
    return 0.5f * x * (1.0f + t);
}

__device__ inline void gload_lds16(const void* g, void* l) {
    __builtin_amdgcn_global_load_lds(
        (const __attribute__((address_space(1))) void*)g,
        (__attribute__((address_space(3))) void*)l, 16, 0, 0);
}

// ---------------------------------------------------------------- cvt x ----
__global__ __launch_bounds__(256) void cvt_kernel(
    const float* __restrict__ in, unsigned short* __restrict__ out, long n4)
{
    long i = (long)blockIdx.x * 256 + threadIdx.x;
    if (i >= n4) return;
    float4 v = ((const float4*)in)[i];
    union { unsigned short u[4]; uint2 q; } r;
    r.u[0] = f2bf(v.x); r.u[1] = f2bf(v.y); r.u[2] = f2bf(v.z); r.u[3] = f2bf(v.w);
    ((uint2*)out)[i] = r.q;
}

// --------------------------------------------- transpose + cvt (weights) ----
__global__ __launch_bounds__(256) void transpose_cvt(
    const float* __restrict__ in, unsigned short* __restrict__ out,
    int R, int Cc, int RT, int CT)
{
    __shared__ float lds[64][65];
    int bx = blockIdx.x;
    int e  = bx / (RT * CT);
    int rem = bx % (RT * CT);
    int rt = rem / CT, ct = rem % CT;
    const float* ine = in + (long)e * R * Cc;
    unsigned short* oute = out + (long)e * R * Cc;
    long r0 = (long)rt * 64, c0 = (long)ct * 64;
    int t = threadIdx.x;

    int lr = t >> 4, lc = t & 15;
#pragma unroll
    for (int ii = 0; ii < 4; ++ii) {
        int r = lr + ii * 16;
        float4 v = *(const float4*)(ine + (r0 + r) * Cc + c0 + lc * 4);
        lds[r][lc * 4 + 0] = v.x; lds[r][lc * 4 + 1] = v.y;
        lds[r][lc * 4 + 2] = v.z; lds[r][lc * 4 + 3] = v.w;
    }
    __syncthreads();

    int nl = t >> 3, kv = t & 7;
#pragma unroll
    for (int ii = 0; ii < 2; ++ii) {
        int n = nl + ii * 32;
        union { unsigned short u[8]; uint4 q; } r;
#pragma unroll
        for (int j = 0; j < 8; ++j) r.u[j] = f2bf(lds[kv * 8 + j][n]);
        *(uint4*)(oute + (c0 + n) * R + r0 + kv * 8) = r.q;
    }
}

// ------------------------------------------------------------------ GEMM ----
// LDS: A only. Slot = {A-k0 16KB, A-k1 16KB}; 2 slots = 64KB static.
#define REG_A1 16384
#define SLOT_B 32768

#define MFMA16(d, a, b) d = __builtin_amdgcn_mfma_f32_16x16x32_bf16(a, b, d, 0, 0, 0)
#define CHECKPOINT(N) do { \
    asm volatile("s_waitcnt vmcnt(" #N ")" ::: "memory"); \
    __builtin_amdgcn_s_barrier(); } while (0)

template <bool GELU, bool OUT_BF16>
__global__ __launch_bounds__(512, 2) void gemm2p(
    const unsigned short* __restrict__ A,
    const unsigned short* __restrict__ Bt,
    const float* __restrict__ bias,
    void* __restrict__ Cout,
    int M, int N, int K,
    long strideAe, long strideBe, long strideCe, int biasStride)
{
    __shared__ char ldsb[2 * SLOT_B];   // 64KB, A only

    constexpr int BM = 256, BN = 256, BK = 64, GRP = 4;
    int MT = M / BM, NT = N / BN;
    int per = MT * NT;
    int nwg = gridDim.x;
    int bid = blockIdx.x;
    int tile = (nwg % 8 == 0) ? (bid & 7) * (nwg >> 3) + (bid >> 3) : bid;
    int e = tile / per, s = tile % per;
    int ng  = s / (MT * GRP);
    int r2  = s % (MT * GRP);
    int mt  = r2 >> 2;
    int nt  = ng * GRP + (r2 & 3);

    const unsigned short* Ae = A  + (long)e * strideAe + (long)mt * BM * K;
    const unsigned short* Be = Bt + (long)e * strideBe + (long)nt * BN * K;

    int tid = threadIdx.x, lane = tid & 63, wid = tid >> 6;
    int wr = wid >> 2, wc = wid & 3;   // 2(M) x 4(N) waves; wave out 128x64

    // ---- A staging (DMA): region = 256 rows x 32 k = 16KB, 2 x 16B/thread
    int g0 = wid * 128 + lane, g1 = g0 + 64;
    long sOff0, sOff1; int sDst0, sDst1;
    { int row = g0 >> 2, col = g0 & 3, sw = col ^ ((row >> 1) & 3);
      sOff0 = (long)row * K + sw * 8; sDst0 = g0 * 16; }
    { int row = g1 >> 2, col = g1 & 3, sw = col ^ ((row >> 1) & 3);
      sOff1 = (long)row * K + sw * 8; sDst1 = g1 * 16; }

    auto stage_A = [&](int ktile, int kreg, int dstByte) {
        long k0 = (long)ktile * BK + kreg * 32;
        gload_lds16(Ae + sOff0 + k0, ldsb + dstByte + sDst0);
        gload_lds16(Ae + sOff1 + k0, ldsb + dstByte + sDst1);
    };

    // ---- B fragment global pointers: frag n = rows wc*64+n*16+(lane&15),
    //      k-quarter (lane>>4)*8. Per phase: 4 x 16B loads.
    const unsigned short* bPtr[4];
#pragma unroll
    for (int n = 0; n < 4; ++n)
        bPtr[n] = Be + (long)(wc * 64 + n * 16 + (lane & 15)) * K + (lane >> 4) * 8;

    f32x4 acc[8][4] = {};
    int KT = K / BK;

    int rbaseA = wr * 128 + (lane & 15);
    int kq = lane >> 4;
    int baseA = rbaseA * 64 + ((kq ^ ((rbaseA >> 1) & 3)) << 4);

    // prologue: A0(0), A1(0), B(P0(0)), A0(1); vmcnt(8) = A0(0) landed
    bf16x8 bA[4], bB[4];
    stage_A(0, 0, 0);
    stage_A(0, 1, REG_A1);
#pragma unroll
    for (int n = 0; n < 4; ++n) bA[n] = *(const bf16x8*)(bPtr[n]);      // T=0 ks0
    stage_A(1, 0, SLOT_B);
    CHECKPOINT(8);

    for (int T = 0; T < KT; ++T) {
        int so = (T & 1) * SLOT_B;
        const char* pA = ldsb + so + baseA;
        int k1 = (T + 1 < KT) ? T + 1 : KT - 1;   // tail clamp: benign
        int k2 = (T + 2 < KT) ? T + 2 : KT - 1;

        // ---- P0: a-ks0 reads (8) || load bB = B(T,ks1) || stage A1(k1) || 32 MFMA(a0,bA)
        bf16x8 a0[8];
#pragma unroll
        for (int m = 0; m < 8; ++m) a0[m] = *(const bf16x8*)(pA + m * 1024);
#pragma unroll
        for (int n = 0; n < 4; ++n)
            bB[n] = *(const bf16x8*)(bPtr[n] + (long)T * BK + 32);
        stage_A(k1, 1, ((k1 & 1) * SLOT_B) + REG_A1);
#pragma unroll
        for (int m = 0; m < 8; ++m)
#pragma unroll
            for (int n = 0; n < 4; ++n)
                MFMA16(acc[m][n], a0[m], bA[n]);
        CHECKPOINT(12);   // A1(T) landed (12 newer: this phase 6 + prev phase 6)

        // ---- P1: a-ks1 reads (8) || load bA = B(T+1,ks0) || stage A0(k2) || 32 MFMA(a1,bB)
        bf16x8 a1[8];
#pragma unroll
        for (int m = 0; m < 8; ++m) a1[m] = *(const bf16x8*)(pA + REG_A1 + m * 1024);
#pragma unroll
        for (int n = 0; n < 4; ++n)
            bA[n] = *(const bf16x8*)(bPtr[n] + (long)k1 * BK);
        stage_A(k2, 0, (k2 & 1) * SLOT_B);
#pragma unroll
        for (int m = 0; m < 8; ++m)
#pragma unroll
            for (int n = 0; n < 4; ++n)
                MFMA16(acc[m][n], a1[m], bB[n]);
        CHECKPOINT(12);   // A0(T+1) landed
    }

    asm volatile("s_waitcnt vmcnt(0)" ::: "memory");  // drain tail DMAs

    // ---- epilogue: C/D layout col=lane&15, row=(lane>>4)*4+j
    const float* be = bias + (long)e * biasStride + nt * BN;
    long cBase = (long)e * strideCe + ((long)mt * BM) * N + (long)nt * BN;
#pragma unroll
    for (int m = 0; m < 8; ++m) {
#pragma unroll
        for (int n = 0; n < 4; ++n) {
            int col = wc * 64 + n * 16 + (lane & 15);
            float bv = be[col];
#pragma unroll
            for (int j = 0; j < 4; ++j) {
                int row = wr * 128 + m * 16 + (lane >> 4) * 4 + j;
                float v = acc[m][n][j] + bv;
                if (GELU) v = gelu_fast(v);
                long idx = cBase + (long)row * N + col;
                if (OUT_BF16) ((unsigned short*)Cout)[idx] = f2bf(v);
                else          ((float*)Cout)[idx] = v;
            }
        }
    }
}

// ------------------------------------------------------------------ host ----
extern "C" void kernel_launch(void* const* d_in, const int* in_sizes, int n_in,
                              void* d_out, int out_size, void* d_ws, size_t ws_size,
                              hipStream_t stream)
{
    const float* x  = (const float*)d_in[0];
    const float* w1 = (const float*)d_in[1];
    const float* b1 = (const float*)d_in[2];
    const float* w2 = (const float*)d_in[3];
    const float* b2 = (const float*)d_in[4];
    float* out = (float*)d_out;

    const long CD = (long)C_ * D_;
    const long DF = (long)D_ * F_;
    const long CF = (long)C_ * F_;
    const long perExpertElems = CD + 2 * DF + CF;
    long ceMax = (long)(ws_size / ((size_t)perExpertElems * 2));
    int CE = (int)(ceMax < 1 ? 1 : (ceMax > E_ ? E_ : ceMax));

    unsigned short* xb  = (unsigned short*)d_ws;
    unsigned short* w1t = xb  + (long)CE * CD;   // [e][F][D]
    unsigned short* w2t = w1t + (long)CE * DF;   // [e][D][F]
    unsigned short* h   = w2t + (long)CE * DF;   // [e][C][F]

    for (int e0 = 0; e0 < E_; e0 += CE) {
        int ce = (E_ - e0) < CE ? (E_ - e0) : CE;

        long n4 = (long)ce * CD / 4;
        cvt_kernel<<<(int)((n4 + 255) / 256), 256, 0, stream>>>(
            x + (long)e0 * CD, xb, n4);

        transpose_cvt<<<ce * (D_ / 64) * (F_ / 64), 256, 0, stream>>>(
            w1 + (long)e0 * DF, w1t, D_, F_, D_ / 64, F_ / 64);

        transpose_cvt<<<ce * (F_ / 64) * (D_ / 64), 256, 0, stream>>>(
            w2 + (long)e0 * DF, w2t, F_, D_, F_ / 64, D_ / 64);

        gemm2p<true, true><<<ce * (C_ / 256) * (F_ / 256), 512, 0, stream>>>(
            xb, w1t, b1 + (long)e0 * F_, (void*)h,
            C_, F_, D_, CD, DF, CF, F_);

        gemm2p<false, false><<<ce * (C_ / 256) * (D_ / 256), 512, 0, stream>>>(
            h, w2t, b2 + (long)e0 * D_, (void*)(out + (long)e0 * CD),
            C_, D_, F_, CF, DF, CD, D_);
    }
}

// Round 13
// 1358.172 us; speedup vs baseline: 1.2826x; 1.2826x over previous
//
#include <hip/hip_runtime.h>
#include <hip/hip_bf16.h>

// Grouped experts FFN. E=8, C=2048, D=2048, F=8192.
// y[e] = GELU(x[e] @ W1[e] + b1[e]) @ W2[e] + b2[e]
// R13 = exact revert to R7/R11, the measured best (1358/1360 us):
//   256x256 tile, BK=64, 8 waves (2Mx4N), 128KB dynamic LDS (2 slots x 4
//   16KB regions), GROUP_N=4 raster + XCD chunking, 2 counted-vmcnt phases
//   per K-tile with NO internal barrier: {12 ds_read_b128 || 32 MFMA ||
//   stage 2 regions} then s_waitcnt vmcnt(8) + s_barrier.
//   GEMMs ~900 TF each; MfmaUtil ~44%, conflicts 0, FETCH ~= ideal.
//   Alternatives all tested and regressed (R3-R6, R8-R10, R12).

#define E_ 8
#define C_ 2048
#define D_ 2048
#define F_ 8192

typedef short bf16x8 __attribute__((ext_vector_type(8)));
typedef float f32x4  __attribute__((ext_vector_type(4)));

__device__ inline unsigned short f2bf(float f) {
    unsigned u = __float_as_uint(f);
    u += 0x7fffu + ((u >> 16) & 1u);
    return (unsigned short)(u >> 16);
}

__device__ inline float gelu_fast(float x) {
    float z = 0.7978845608028654f * (x + 0.044715f * x * x * x);
    float e = __expf(-2.0f * fabsf(z));
    float t = (1.0f - e) / (1.0f + e);
    t = copysignf(t, z);
    return 0.5f * x * (1.0f + t);
}

__device__ inline void gload_lds16(const void* g, void* l) {
    __builtin_amdgcn_global_load_lds(
        (const __attribute__((address_space(1))) void*)g,
        (__attribute__((address_space(3))) void*)l, 16, 0, 0);
}

// ---------------------------------------------------------------- cvt x ----
__global__ __launch_bounds__(256) void cvt_kernel(
    const float* __restrict__ in, unsigned short* __restrict__ out, long n4)
{
    long i = (long)blockIdx.x * 256 + threadIdx.x;
    if (i >= n4) return;
    float4 v = ((const float4*)in)[i];
    union { unsigned short u[4]; uint2 q; } r;
    r.u[0] = f2bf(v.x); r.u[1] = f2bf(v.y); r.u[2] = f2bf(v.z); r.u[3] = f2bf(v.w);
    ((uint2*)out)[i] = r.q;
}

// --------------------------------------------- transpose + cvt (weights) ----
__global__ __launch_bounds__(256) void transpose_cvt(
    const float* __restrict__ in, unsigned short* __restrict__ out,
    int R, int Cc, int RT, int CT)
{
    __shared__ float lds[64][65];
    int bx = blockIdx.x;
    int e  = bx / (RT * CT);
    int rem = bx % (RT * CT);
    int rt = rem / CT, ct = rem % CT;
    const float* ine = in + (long)e * R * Cc;
    unsigned short* oute = out + (long)e * R * Cc;
    long r0 = (long)rt * 64, c0 = (long)ct * 64;
    int t = threadIdx.x;

    int lr = t >> 4, lc = t & 15;
#pragma unroll
    for (int ii = 0; ii < 4; ++ii) {
        int r = lr + ii * 16;
        float4 v = *(const float4*)(ine + (r0 + r) * Cc + c0 + lc * 4);
        lds[r][lc * 4 + 0] = v.x; lds[r][lc * 4 + 1] = v.y;
        lds[r][lc * 4 + 2] = v.z; lds[r][lc * 4 + 3] = v.w;
    }
    __syncthreads();

    int nl = t >> 3, kv = t & 7;
#pragma unroll
    for (int ii = 0; ii < 2; ++ii) {
        int n = nl + ii * 32;
        union { unsigned short u[8]; uint4 q; } r;
#pragma unroll
        for (int j = 0; j < 8; ++j) r.u[j] = f2bf(lds[kv * 8 + j][n]);
        *(uint4*)(oute + (c0 + n) * R + r0 + kv * 8) = r.q;
    }
}

// ------------------------------------------------------------------ GEMM ----
#define REG_A0 0
#define REG_A1 16384
#define REG_B0 32768
#define REG_B1 49152
#define SLOT_B 65536

#define MFMA16(d, a, b) d = __builtin_amdgcn_mfma_f32_16x16x32_bf16(a, b, d, 0, 0, 0)
#define CHECKPOINT8() do { \
    asm volatile("s_waitcnt vmcnt(8)" ::: "memory"); \
    __builtin_amdgcn_s_barrier(); } while (0)

template <bool GELU, bool OUT_BF16>
__global__ __launch_bounds__(512, 2) void gemm2p(
    const unsigned short* __restrict__ A,
    const unsigned short* __restrict__ Bt,
    const float* __restrict__ bias,
    void* __restrict__ Cout,
    int M, int N, int K,
    long strideAe, long strideBe, long strideCe, int biasStride)
{
    extern __shared__ char ldsb[];   // 131072 bytes

    constexpr int BM = 256, BN = 256, BK = 64, GRP = 4;
    int MT = M / BM, NT = N / BN;
    int per = MT * NT;
    int nwg = gridDim.x;
    int bid = blockIdx.x;
    int tile = (nwg % 8 == 0) ? (bid & 7) * (nwg >> 3) + (bid >> 3) : bid;
    int e = tile / per, s = tile % per;
    int ng  = s / (MT * GRP);
    int r2  = s % (MT * GRP);
    int mt  = r2 >> 2;
    int nt  = ng * GRP + (r2 & 3);

    const unsigned short* Ae = A  + (long)e * strideAe + (long)mt * BM * K;
    const unsigned short* Be = Bt + (long)e * strideBe + (long)nt * BN * K;

    int tid = threadIdx.x, lane = tid & 63, wid = tid >> 6;
    int wr = wid >> 2, wc = wid & 3;   // 2(M) x 4(N) waves; wave out 128x64

    // staging: per region (256r x 32k = 16KB) each thread moves 2 x 16B.
    int g0 = wid * 128 + lane, g1 = g0 + 64;
    long sOff0, sOff1; int sDst0, sDst1;
    { int row = g0 >> 2, col = g0 & 3, sw = col ^ ((row >> 1) & 3);
      sOff0 = (long)row * K + sw * 8; sDst0 = g0 * 16; }
    { int row = g1 >> 2, col = g1 & 3, sw = col ^ ((row >> 1) & 3);
      sOff1 = (long)row * K + sw * 8; sDst1 = g1 * 16; }

    auto stage_region = [&](const unsigned short* base, int ktile, int kreg, int dstByte) {
        long k0 = (long)ktile * BK + kreg * 32;
        gload_lds16(base + sOff0 + k0, ldsb + dstByte + sDst0);
        gload_lds16(base + sOff1 + k0, ldsb + dstByte + sDst1);
    };

    f32x4 acc[8][4] = {};
    int KT = K / BK;

    int rbaseA = wr * 128 + (lane & 15);
    int rbaseB = wc * 64  + (lane & 15);
    int kq = lane >> 4;
    int baseA = rbaseA * 64 + ((kq ^ ((rbaseA >> 1) & 3)) << 4);
    int baseB = REG_B0 + rbaseB * 64 + ((kq ^ ((rbaseB >> 1) & 3)) << 4);

    // prologue: A0B0(0), A1B1(0), A0B0(1); vmcnt(8) = A0B0(0) landed
    stage_region(Ae, 0, 0, REG_A0);
    stage_region(Be, 0, 0, REG_B0);
    stage_region(Ae, 0, 1, REG_A1);
    stage_region(Be, 0, 1, REG_B1);
    stage_region(Ae, 1, 0, SLOT_B + REG_A0);
    stage_region(Be, 1, 0, SLOT_B + REG_B0);
    CHECKPOINT8();

    for (int T = 0; T < KT; ++T) {
        int so = (T & 1) * SLOT_B;
        const char* pA = ldsb + so + baseA;
        const char* pB = ldsb + so + baseB;
        int k1 = (T + 1 < KT) ? T + 1 : KT - 1;   // tail clamp: benign re-stage
        int k2 = (T + 2 < KT) ? T + 2 : KT - 1;
        int so1 = (k1 & 1) * SLOT_B;
        int so2 = (k2 & 1) * SLOT_B;

        // ---- P0: ks0 reads (12) || stage A1B1(k1) || 32 MFMA
        bf16x8 a0[8], b0[4];
#pragma unroll
        for (int n = 0; n < 4; ++n) b0[n] = *(const bf16x8*)(pB + n * 1024);
#pragma unroll
        for (int m = 0; m < 8; ++m) a0[m] = *(const bf16x8*)(pA + m * 1024);
        stage_region(Ae, k1, 1, so1 + REG_A1);
        stage_region(Be, k1, 1, so1 + REG_B1);
#pragma unroll
        for (int m = 0; m < 8; ++m)
#pragma unroll
            for (int n = 0; n < 4; ++n)
                MFMA16(acc[m][n], a0[m], b0[n]);
        CHECKPOINT8();   // A1B1(T) landed (8 newer in flight)

        // ---- P1: ks1 reads (12) || stage A0B0(k2) || 32 MFMA
        bf16x8 a1[8], b1[4];
#pragma unroll
        for (int n = 0; n < 4; ++n) b1[n] = *(const bf16x8*)(pB + 16384 + n * 1024);
#pragma unroll
        for (int m = 0; m < 8; ++m) a1[m] = *(const bf16x8*)(pA + 16384 + m * 1024);
        stage_region(Ae, k2, 0, so2 + REG_A0);
        stage_region(Be, k2, 0, so2 + REG_B0);
#pragma unroll
        for (int m = 0; m < 8; ++m)
#pragma unroll
            for (int n = 0; n < 4; ++n)
                MFMA16(acc[m][n], a1[m], b1[n]);
        CHECKPOINT8();   // A0B0(T+1) landed
    }

    asm volatile("s_waitcnt vmcnt(0)" ::: "memory");  // drain tail DMAs

    // ---- epilogue: C/D layout col=lane&15, row=(lane>>4)*4+j
    const float* be = bias + (long)e * biasStride + nt * BN;
    long cBase = (long)e * strideCe + ((long)mt * BM) * N + (long)nt * BN;
#pragma unroll
    for (int m = 0; m < 8; ++m) {
#pragma unroll
        for (int n = 0; n < 4; ++n) {
            int col = wc * 64 + n * 16 + (lane & 15);
            float bv = be[col];
#pragma unroll
            for (int j = 0; j < 4; ++j) {
                int row = wr * 128 + m * 16 + (lane >> 4) * 4 + j;
                float v = acc[m][n][j] + bv;
                if (GELU) v = gelu_fast(v);
                long idx = cBase + (long)row * N + col;
                if (OUT_BF16) ((unsigned short*)Cout)[idx] = f2bf(v);
                else          ((float*)Cout)[idx] = v;
            }
        }
    }
}

// ------------------------------------------------------------------ host ----
extern "C" void kernel_launch(void* const* d_in, const int* in_sizes, int n_in,
                              void* d_out, int out_size, void* d_ws, size_t ws_size,
                              hipStream_t stream)
{
    const float* x  = (const float*)d_in[0];
    const float* w1 = (const float*)d_in[1];
    const float* b1 = (const float*)d_in[2];
    const float* w2 = (const float*)d_in[3];
    const float* b2 = (const float*)d_in[4];
    float* out = (float*)d_out;

    (void)hipFuncSetAttribute((const void*)gemm2p<true, true>,
                              hipFuncAttributeMaxDynamicSharedMemorySize, 131072);
    (void)hipFuncSetAttribute((const void*)gemm2p<false, false>,
                              hipFuncAttributeMaxDynamicSharedMemorySize, 131072);

    const long CD = (long)C_ * D_;
    const long DF = (long)D_ * F_;
    const long CF = (long)C_ * F_;
    const long perExpertElems = CD + 2 * DF + CF;
    long ceMax = (long)(ws_size / ((size_t)perExpertElems * 2));
    int CE = (int)(ceMax < 1 ? 1 : (ceMax > E_ ? E_ : ceMax));

    unsigned short* xb  = (unsigned short*)d_ws;
    unsigned short* w1t = xb  + (long)CE * CD;   // [e][F][D]
    unsigned short* w2t = w1t + (long)CE * DF;   // [e][D][F]
    unsigned short* h   = w2t + (long)CE * DF;   // [e][C][F]

    for (int e0 = 0; e0 < E_; e0 += CE) {
        int ce = (E_ - e0) < CE ? (E_ - e0) : CE;

        long n4 = (long)ce * CD / 4;
        cvt_kernel<<<(int)((n4 + 255) / 256), 256, 0, stream>>>(
            x + (long)e0 * CD, xb, n4);

        transpose_cvt<<<ce * (D_ / 64) * (F_ / 64), 256, 0, stream>>>(
            w1 + (long)e0 * DF, w1t, D_, F_, D_ / 64, F_ / 64);

        transpose_cvt<<<ce * (F_ / 64) * (D_ / 64), 256, 0, stream>>>(
            w2 + (long)e0 * DF, w2t, F_, D_, F_ / 64, D_ / 64);

        gemm2p<true, true><<<ce * (C_ / 256) * (F_ / 256), 512, 131072, stream>>>(
            xb, w1t, b1 + (long)e0 * F_, (void*)h,
            C_, F_, D_, CD, DF, CF, F_);

        gemm2p<false, false><<<ce * (C_ / 256) * (D_ / 256), 512, 131072, stream>>>(
            h, w2t, b2 + (long)e0 * D_, (void*)(out + (long)e0 * CD),
            C_, D_, F_, CF, DF, CD, D_);
    }
}